// Round 17
// baseline (151.578 us; speedup 1.0000x reference)
//
#include <hip/hip_runtime.h>
#include <hip/hip_bf16.h>

constexpr int B = 512, N = 64, E = 512, NE = B * E;

typedef __attribute__((ext_vector_type(8))) short bf8v;
typedef __attribute__((ext_vector_type(4))) float f32x4;
typedef unsigned short u16;

__device__ __forceinline__ u16 f2bf(float f) {
  unsigned u = __builtin_bit_cast(unsigned, f);
  u += 0x7FFFu + ((u >> 16) & 1u);
  return (u16)(u >> 16);
}

__device__ __forceinline__ int cmin(int a, int b) { return a < b ? a : b; }

// =================== fused 3-layer GCN via bf16 MFMA (unchanged) ===================
template <int DIN, int KP, int DOUT, bool STORE_NEXT>
__device__ __forceinline__ void gcn_layer_mfma(
    const u16* __restrict__ Ab, u16* __restrict__ Xb, u16* __restrict__ Hb,
    u16* __restrict__ Wb, const float* __restrict__ W,
    const float* __restrict__ bias, u16* __restrict__ fout, int g, int t) {
  for (int i = t; i < DOUT * KP; i += 256) {
    int c = i / KP, k = i % KP;
    u16 v = 0;
    if (k < DIN) v = f2bf(W[k * DOUT + c]);
    Wb[c * 72 + k] = v;
  }
  __syncthreads();
  const int w4 = t >> 6, lane = t & 63;
  const int r16 = lane & 15, kg = lane >> 4;
  constexpr int CT = DOUT / 16;
#pragma unroll
  for (int ct = 0; ct < CT; ++ct) {
    f32x4 acc = {0.f, 0.f, 0.f, 0.f};
#pragma unroll
    for (int ks = 0; ks < KP; ks += 32) {
      bf8v a = *(const bf8v*)&Xb[(w4 * 16 + r16) * 72 + ks + kg * 8];
      bf8v bb = *(const bf8v*)&Wb[(ct * 16 + r16) * 72 + ks + kg * 8];
      acc = __builtin_amdgcn_mfma_f32_16x16x32_bf16(a, bb, acc, 0, 0, 0);
    }
    ushort4 pk;
    pk.x = f2bf(acc[0]); pk.y = f2bf(acc[1]);
    pk.z = f2bf(acc[2]); pk.w = f2bf(acc[3]);
    *(ushort4*)&Hb[(ct * 16 + r16) * 72 + w4 * 16 + kg * 4] = pk;
  }
  __syncthreads();
#pragma unroll
  for (int ct = 0; ct < CT; ++ct) {
    f32x4 acc = {0.f, 0.f, 0.f, 0.f};
#pragma unroll
    for (int ks = 0; ks < 64; ks += 32) {
      bf8v a = *(const bf8v*)&Ab[(w4 * 16 + r16) * 72 + ks + kg * 8];
      bf8v bb = *(const bf8v*)&Hb[(ct * 16 + r16) * 72 + ks + kg * 8];
      acc = __builtin_amdgcn_mfma_f32_16x16x32_bf16(a, bb, acc, 0, 0, 0);
    }
    const int c = ct * 16 + r16;
    const float bv = bias[c];
#pragma unroll
    for (int j = 0; j < 4; ++j) {
      float st = acc[j] + bv;
      const int d = w4 * 16 + kg * 4 + j;
      fout[(size_t)g * N * DOUT + (size_t)d * DOUT + c] = f2bf(st);
      if (STORE_NEXT) Xb[d * 72 + c] = f2bf(fmaxf(st, 0.f));
    }
  }
  __syncthreads();
}

__global__ __launch_bounds__(256) void gcn_fused(
    const float* __restrict__ xq, const float* __restrict__ xc,
    const float* __restrict__ W1, const float* __restrict__ b1,
    const float* __restrict__ W2, const float* __restrict__ b2,
    const float* __restrict__ W3, const float* __restrict__ b3,
    const int* __restrict__ eq, const int* __restrict__ ec,
    u16* __restrict__ f1q, u16* __restrict__ f1c,
    u16* __restrict__ f2q, u16* __restrict__ f2c,
    u16* __restrict__ f3q, u16* __restrict__ f3c) {
  __shared__ __align__(16) float Af[64 * 68];   // later aliased as Wb
  __shared__ __align__(16) u16 Ab[64 * 72];
  __shared__ __align__(16) u16 Xb[64 * 72];
  __shared__ __align__(16) u16 Hb[64 * 72];
  __shared__ float dl[N];
  __shared__ int cnt[N];
  u16* Wb = (u16*)Af;
  const int g = blockIdx.x, t = threadIdx.x;
  const float* x = blockIdx.y ? xc : xq;
  const int* edges = blockIdx.y ? ec : eq;
  u16* o1 = blockIdx.y ? f1c : f1q;
  u16* o2 = blockIdx.y ? f2c : f2q;
  u16* o3 = blockIdx.y ? f3c : f3q;
  for (int i = t; i < 64 * 32; i += 256) {
    int n = i >> 5, k = i & 31;
    u16 v = 0;
    if (k < 16) v = f2bf(x[(size_t)g * 1024 + n * 16 + k]);
    Xb[n * 72 + k] = v;
  }
  for (int i = t; i < 64 * 68; i += 256) Af[i] = 0.f;
  if (t < N) cnt[t] = 1;
  __syncthreads();
  const int* srcp = edges + (size_t)g * E;
  const int* dstp = edges + NE + (size_t)g * E;
  for (int j = t; j < E; j += 256) atomicAdd(&cnt[dstp[j] & 63], 1);
  __syncthreads();
  if (t < N) dl[t] = rsqrtf((float)cnt[t]);
  __syncthreads();
  for (int j = t; j < E; j += 256) {
    int s = srcp[j] & 63, d = dstp[j] & 63;
    atomicAdd(&Af[d * 68 + s], dl[s] * dl[d]);
  }
  if (t < N) atomicAdd(&Af[t * 68 + t], dl[t] * dl[t]);
  __syncthreads();
  for (int i = t; i < 4096; i += 256) {
    int d = i >> 6, s = i & 63;
    Ab[d * 72 + s] = f2bf(Af[d * 68 + s]);
  }
  __syncthreads();
  gcn_layer_mfma<16, 32, 64, true>(Ab, Xb, Hb, Wb, W1, b1, o1, g, t);
  gcn_layer_mfma<64, 64, 32, true>(Ab, Xb, Hb, Wb, W2, b2, o2, g, t);
  gcn_layer_mfma<32, 32, 16, false>(Ab, Xb, Hb, Wb, W3, b3, o3, g, t);
}

// =================== fused sim (bf16 MFMA) + conv1 (fp32 VALU), oc-split z=2 ===================
__global__ __launch_bounds__(256, 4) void simconv1(
    const u16* __restrict__ f1q, const u16* __restrict__ f1c,
    const u16* __restrict__ f2q, const u16* __restrict__ f2c,
    const u16* __restrict__ f3q, const u16* __restrict__ f3c,
    const float* __restrict__ w, const float* __restrict__ bias,
    u16* __restrict__ out) {
  constexpr int PS = 68, QS = 72;
  __shared__ __align__(16) u16 Qs[64 * QS];
  __shared__ __align__(16) u16 Cs[64 * QS];
  __shared__ __align__(16) float simp[68 * 68];
  __shared__ float wls[25 * 8];  // [tap][oc]
  __shared__ float bls[8];
  const int b = blockIdx.x, m = blockIdx.y, zb = blockIdx.z, t = threadIdx.x;
  for (int i = t; i < 68 * 68; i += 256) simp[i] = 0.f;
  if (t < 200) {
    int oc = t / 25, tap = t % 25;
    wls[tap * 8 + oc] = w[m * 200 + t];
  }
  if (t < 8) bls[t] = bias[m * 8 + t];
  const u16* fq = (m == 0) ? f1q : (m == 1) ? f2q : f3q;
  const u16* fc = (m == 0) ? f1c : (m == 1) ? f2c : f3c;
  const int D = 64 >> m;
  const int SEG = D >> 3;
  for (int i = t; i < 64 * SEG; i += 256) {
    int n = i / SEG, s = i - n * SEG;
    *(uint4*)&Qs[n * QS + s * 8] = *(const uint4*)&fq[(size_t)b * 64 * D + n * D + s * 8];
    *(uint4*)&Cs[n * QS + s * 8] = *(const uint4*)&fc[(size_t)b * 64 * D + n * D + s * 8];
  }
  if (m == 2 && t < 128) {
    int n = t >> 1, s = t & 1;
    uint4 z = {0u, 0u, 0u, 0u};
    *(uint4*)&Qs[n * QS + 16 + s * 8] = z;
    *(uint4*)&Cs[n * QS + 16 + s * 8] = z;
  }
  __syncthreads();
  const int w4 = t >> 6, lane = t & 63;
  const int r16 = lane & 15, kg = lane >> 4;
  const int Kpad = (m == 0) ? 64 : 32;
#pragma unroll 1
  for (int ct = 0; ct < 4; ++ct) {
    f32x4 acc = {0.f, 0.f, 0.f, 0.f};
    for (int ks = 0; ks < Kpad; ks += 32) {
      bf8v a = *(const bf8v*)&Qs[(w4 * 16 + r16) * QS + ks + kg * 8];
      bf8v bb = *(const bf8v*)&Cs[(ct * 16 + r16) * QS + ks + kg * 8];
      acc = __builtin_amdgcn_mfma_f32_16x16x32_bf16(a, bb, acc, 0, 0, 0);
    }
#pragma unroll
    for (int j = 0; j < 4; ++j)
      simp[(w4 * 16 + kg * 4 + j + 2) * PS + ct * 16 + r16 + 2] = acc[j];
  }
  __syncthreads();
  const int gy = t >> 4, gx = t & 15;
  float pr[8][8];
#pragma unroll
  for (int yy = 0; yy < 8; ++yy) {
    float4 a = *(const float4*)&simp[(4 * gy + yy) * PS + 4 * gx];
    float4 bb = *(const float4*)&simp[(4 * gy + yy) * PS + 4 * gx + 4];
    pr[yy][0] = a.x; pr[yy][1] = a.y; pr[yy][2] = a.z; pr[yy][3] = a.w;
    pr[yy][4] = bb.x; pr[yy][5] = bb.y; pr[yy][6] = bb.z; pr[yy][7] = bb.w;
  }
  u16* op = out + (size_t)(b * 3 + m) * 8192;
#pragma unroll 1
  for (int p2 = 2 * zb; p2 < 2 * zb + 2; ++p2) {
    float acc[2][16];
#pragma unroll
    for (int p = 0; p < 16; ++p) { acc[0][p] = 0.f; acc[1][p] = 0.f; }
#pragma unroll
    for (int ky = 0; ky < 5; ++ky)
#pragma unroll
      for (int kx = 0; kx < 5; ++kx) {
        float2 wv = *(const float2*)&wls[(ky * 5 + kx) * 8 + p2 * 2];
#pragma unroll
        for (int dy = 0; dy < 4; ++dy)
#pragma unroll
          for (int dx = 0; dx < 4; ++dx) {
            float rv = pr[ky + dy][kx + dx];
            acc[0][dy * 4 + dx] += rv * wv.x;
            acc[1][dy * 4 + dx] += rv * wv.y;
          }
      }
    float b0 = bls[p2 * 2], b1 = bls[p2 * 2 + 1];
#pragma unroll
    for (int ay = 0; ay < 2; ++ay)
#pragma unroll
      for (int ax = 0; ax < 2; ++ax) {
        float v0 = fmaxf(fmaxf(acc[0][(2 * ay) * 4 + 2 * ax], acc[0][(2 * ay) * 4 + 2 * ax + 1]),
                         fmaxf(acc[0][(2 * ay + 1) * 4 + 2 * ax], acc[0][(2 * ay + 1) * 4 + 2 * ax + 1]));
        float v1 = fmaxf(fmaxf(acc[1][(2 * ay) * 4 + 2 * ax], acc[1][(2 * ay) * 4 + 2 * ax + 1]),
                         fmaxf(acc[1][(2 * ay + 1) * 4 + 2 * ax], acc[1][(2 * ay + 1) * 4 + 2 * ax + 1]));
        v0 = fmaxf(v0 + b0, 0.f);
        v1 = fmaxf(v1 + b1, 0.f);
        unsigned pack = (unsigned)f2bf(v0) | ((unsigned)f2bf(v1) << 16);
        *(unsigned*)&op[(size_t)(((2 * gy + ay) * 32) + (2 * gx + ax)) * 8 + p2 * 2] = pack;
      }
  }
}

// =================== prep: wcvt (blocks 0..383) + wprep (blocks 384..579) ===================
__global__ __launch_bounds__(256) void prep_kernel(
    const float* __restrict__ lw1, const float* __restrict__ cw2,
    const float* __restrict__ cw3, u16* __restrict__ wT,
    u16* __restrict__ w2p, u16* __restrict__ w3p) {
  const int t = threadIdx.x;
  if (blockIdx.x < 384) {
    __shared__ float tile[64][65];
    const int k0 = (blockIdx.x % 96) * 64, c0 = (blockIdx.x / 96) * 64;
    for (int i = t; i < 4096; i += 256) {
      int r = i >> 6, c = i & 63;
      tile[r][c] = lw1[(size_t)(k0 + r) * 256 + c0 + c];
    }
    __syncthreads();
    for (int i = t; i < 4096; i += 256) {
      int c = i >> 6, k = i & 63;
      wT[(size_t)(c0 + c) * 6144 + k0 + k] = f2bf(tile[k][c]);
    }
    return;
  }
  int i = (blockIdx.x - 384) * 256 + t;
  if (i < 3 * 7 * 16 * 40) {
    int m = i / 4480, r = i % 4480;
    int k = r % 40, rest = r / 40, oc = rest & 15, st = rest >> 4;
    u16 v = 0;
    if (k < 32) {
      int sl = k >> 3, ci = k & 7, tap = st * 4 + sl;
      if (tap < 25) v = f2bf(cw2[((size_t)(m * 16 + oc) * 8 + ci) * 25 + tap]);
    }
    w2p[i] = v;
  }
  if (i < 3 * 26 * 16 * 40) {
    int m = i / 16640, r = i % 16640;
    int k = r % 40, rest = r / 40, oc16 = rest & 15, sthalf = rest >> 4;
    int half = sthalf & 1, st = sthalf >> 1;
    u16 v = 0;
    if (k < 32) {
      int sl = k >> 4, ci = k & 15, tap = st * 2 + sl;
      int oc = half * 16 + oc16;
      if (tap < 25) v = f2bf(cw3[((size_t)(m * 32 + oc) * 16 + ci) * 25 + tap]);
    }
    w3p[i] = v;
  }
}

// =================== conv2+conv3 fused (unchanged) ===================
__global__ __launch_bounds__(256) void conv23_mfma(
    const u16* __restrict__ in, const u16* __restrict__ w2p,
    const float* __restrict__ cb2, const u16* __restrict__ w3p,
    const float* __restrict__ cb3, u16* __restrict__ feat) {
  constexpr int PW2 = 36, PW3 = 20, BS = 40;
  __shared__ __align__(16) u16 uni[16640];
  __shared__ __align__(16) u16 p2s[PW3 * PW3 * 16];
  __shared__ float bls2[16];
  __shared__ float bls3[32];
  const int b = blockIdx.x, m = blockIdx.y, t = threadIdx.x;
  u16* ins2 = uni;
  u16* w2ls = uni + 10368;
  const size_t ibase = (size_t)(b * 3 + m) * 8192;
  for (int i = t; i < PW2 * PW2; i += 256) {
    int y = i / PW2, x = i % PW2;
    uint4 v = {0u, 0u, 0u, 0u};
    if (y >= 2 && y < 34 && x >= 2 && x < 34)
      v = *(const uint4*)&in[ibase + (size_t)((y - 2) * 32 + (x - 2)) * 8];
    *(uint4*)&ins2[i * 8] = v;
  }
  {
    const u16* wsrc = w2p + m * 4480;
    for (int i = t; i < 560; i += 256) *(uint4*)&w2ls[i * 8] = *(const uint4*)&wsrc[i * 8];
  }
  {
    uint4 z = {0u, 0u, 0u, 0u};
    for (int i = t; i < 800; i += 256) *(uint4*)&p2s[i * 8] = z;
  }
  if (t < 16) bls2[t] = cb2[m * 16 + t];
  if (t >= 32 && t < 64) bls3[t - 32] = cb3[m * 32 + (t - 32)];
  __syncthreads();
  const int wv = t >> 6, lane = t & 63;
  const int oc = lane & 15, g = lane >> 4;
  {
    const int xt = wv & 1, ypb = wv >> 1;
    const int x = xt * 16 + oc;
    __builtin_amdgcn_s_setprio(1);
#pragma unroll 1
    for (int grp = 0; grp < 2; ++grp) {
      f32x4 acc[4][2];
#pragma unroll
      for (int i = 0; i < 4; ++i) {
        acc[i][0] = (f32x4){0.f, 0.f, 0.f, 0.f};
        acc[i][1] = (f32x4){0.f, 0.f, 0.f, 0.f};
      }
#pragma unroll
      for (int st = 0; st < 7; ++st) {
        bf8v bvv = *(const bf8v*)&w2ls[(st * 16 + oc) * BS + g * 8];
        const int c0 = cmin(st * 4 + 0, 24), c1 = cmin(st * 4 + 1, 24);
        const int c2 = cmin(st * 4 + 2, 24), c3 = cmin(st * 4 + 3, 24);
        const int k0 = (c0 / 5) * PW2 + c0 % 5, k1 = (c1 / 5) * PW2 + c1 % 5;
        const int k2 = (c2 / 5) * PW2 + c2 % 5, k3 = (c3 / 5) * PW2 + c3 % 5;
        const int koff = (g == 0) ? k0 : (g == 1) ? k1 : (g == 2) ? k2 : k3;
#pragma unroll
        for (int i = 0; i < 4; ++i) {
          const int y0 = 2 * ypb + 4 * (grp * 4 + i);
          const int abase = (y0 * PW2 + x + koff) * 8;
          bf8v a0 = *(const bf8v*)&ins2[abase];
          acc[i][0] = __builtin_amdgcn_mfma_f32_16x16x32_bf16(a0, bvv, acc[i][0], 0, 0, 0);
          bf8v a1 = *(const bf8v*)&ins2[abase + PW2 * 8];
          acc[i][1] = __builtin_amdgcn_mfma_f32_16x16x32_bf16(a1, bvv, acc[i][1], 0, 0, 0);
        }
      }
      const float bb = bls2[oc];
#pragma unroll
      for (int i = 0; i < 4; ++i) {
        const int yp = ypb + 2 * (grp * 4 + i);
        const float v0 = fmaxf(fmaxf(fmaxf(acc[i][0][0], acc[i][0][1]),
                                     fmaxf(acc[i][1][0], acc[i][1][1])) + bb, 0.f);
        const float v1 = fmaxf(fmaxf(fmaxf(acc[i][0][2], acc[i][0][3]),
                                     fmaxf(acc[i][1][2], acc[i][1][3])) + bb, 0.f);
        const int px = xt * 8 + 2 * g;
        p2s[((yp + 2) * PW3 + (px + 2)) * 16 + oc] = f2bf(v0);
        p2s[((yp + 2) * PW3 + (px + 3)) * 16 + oc] = f2bf(v1);
      }
    }
    __builtin_amdgcn_s_setprio(0);
  }
  __syncthreads();
  {
    const u16* wsrc = w3p + m * 16640;
    for (int i = t; i < 2080; i += 256) *(uint4*)&uni[i * 8] = *(const uint4*)&wsrc[i * 8];
  }
  __syncthreads();
  {
    const int sl = g >> 1, ch = (g & 1) * 8;
    const int half = wv & 1, ypb = wv >> 1;
    u16* fb = feat + (size_t)b * 6144 + m * 2048;
    f32x4 acc[4][2];
#pragma unroll
    for (int i = 0; i < 4; ++i) {
      acc[i][0] = (f32x4){0.f, 0.f, 0.f, 0.f};
      acc[i][1] = (f32x4){0.f, 0.f, 0.f, 0.f};
    }
    __builtin_amdgcn_s_setprio(1);
#pragma unroll
    for (int st = 0; st < 13; ++st) {
      bf8v bvv = *(const bf8v*)&uni[(size_t)((st * 2 + half) * 16 + oc) * BS + g * 8];
      const int c0 = cmin(st * 2 + 0, 24), c1 = cmin(st * 2 + 1, 24);
      const int k0 = (c0 / 5) * PW3 + c0 % 5, k1 = (c1 / 5) * PW3 + c1 % 5;
      const int koff = sl ? k1 : k0;
#pragma unroll
      for (int i = 0; i < 4; ++i) {
        const int y0 = 2 * ypb + 4 * i;
        const int abase = (y0 * PW3 + oc + koff) * 16 + ch;
        bf8v a0 = *(const bf8v*)&p2s[abase];
        acc[i][0] = __builtin_amdgcn_mfma_f32_16x16x32_bf16(a0, bvv, acc[i][0], 0, 0, 0);
        bf8v a1 = *(const bf8v*)&p2s[abase + PW3 * 16];
        acc[i][1] = __builtin_amdgcn_mfma_f32_16x16x32_bf16(a1, bvv, acc[i][1], 0, 0, 0);
      }
    }
    __builtin_amdgcn_s_setprio(0);
    const int ocg = half * 16 + oc;
    const float bb = bls3[ocg];
#pragma unroll
    for (int i = 0; i < 4; ++i) {
      const int yp = ypb + 2 * i;
      const float v0 = fmaxf(fmaxf(fmaxf(acc[i][0][0], acc[i][0][1]),
                                   fmaxf(acc[i][1][0], acc[i][1][1])) + bb, 0.f);
      const float v1 = fmaxf(fmaxf(fmaxf(acc[i][0][2], acc[i][0][3]),
                                   fmaxf(acc[i][1][2], acc[i][1][3])) + bb, 0.f);
      unsigned pack = (unsigned)f2bf(v0) | ((unsigned)f2bf(v1) << 16);
      *(unsigned*)&fb[ocg * 64 + yp * 8 + 2 * g] = pack;
    }
  }
}

// =================== lin1: bf16 MFMA GEMM (unchanged) ===================
__global__ __launch_bounds__(256) void lin1_mfma(const u16* __restrict__ feat,
                                                 const u16* __restrict__ wT,
                                                 float* __restrict__ h1p) {
  constexpr int AS = 72;
  __shared__ __align__(16) u16 As[64 * AS];
  __shared__ __align__(16) u16 Bs[64 * AS];
  const int r0 = blockIdx.x * 64, c0 = blockIdx.y * 64, kb = blockIdx.z * 384;
  const int t = threadIdx.x;
  const int w = t >> 6, lane = t & 63;
  const int row16 = lane & 15, kg = lane >> 4;
  f32x4 acc[4] = {{0.f, 0.f, 0.f, 0.f}, {0.f, 0.f, 0.f, 0.f},
                  {0.f, 0.f, 0.f, 0.f}, {0.f, 0.f, 0.f, 0.f}};
  const int lr = t >> 2, lk = (t & 3) * 16;
#pragma unroll 1
  for (int st = 0; st < 6; ++st) {
    __syncthreads();
    const int ks = kb + st * 64;
    {
      const u16* srcA = feat + (size_t)(r0 + lr) * 6144 + ks + lk;
      uint4 a0 = *(const uint4*)srcA;
      uint4 a1 = *(const uint4*)(srcA + 8);
      *(uint4*)&As[lr * AS + lk] = a0;
      *(uint4*)&As[lr * AS + lk + 8] = a1;
      const u16* srcB = wT + (size_t)(c0 + lr) * 6144 + ks + lk;
      uint4 b0 = *(const uint4*)srcB;
      uint4 b1 = *(const uint4*)(srcB + 8);
      *(uint4*)&Bs[lr * AS + lk] = b0;
      *(uint4*)&Bs[lr * AS + lk + 8] = b1;
    }
    __syncthreads();
#pragma unroll
    for (int kk = 0; kk < 2; ++kk) {
      bf8v a = *(const bf8v*)&As[(w * 16 + row16) * AS + kk * 32 + kg * 8];
#pragma unroll
      for (int ct = 0; ct < 4; ++ct) {
        bf8v bb = *(const bf8v*)&Bs[(ct * 16 + row16) * AS + kk * 32 + kg * 8];
        acc[ct] = __builtin_amdgcn_mfma_f32_16x16x32_bf16(a, bb, acc[ct], 0, 0, 0);
      }
    }
  }
  float* out = h1p + (size_t)blockIdx.z * 131072;
#pragma unroll
  for (int ct = 0; ct < 4; ++ct)
#pragma unroll
    for (int j = 0; j < 4; ++j)
      out[(size_t)(r0 + w * 16 + kg * 4 + j) * 256 + c0 + ct * 16 + row16] = acc[ct][j];
}

// =================== head (unchanged) ===================
__global__ __launch_bounds__(256) void head_kernel(
    const float* __restrict__ h1p, const float* __restrict__ b1,
    const float* __restrict__ w2, const float* __restrict__ b2,
    const float* __restrict__ sw, const float* __restrict__ sb,
    float* __restrict__ out) {
  constexpr int HS = 260;
  __shared__ __align__(16) float h1s[16 * HS];
  __shared__ __align__(16) float w2s[256 * 16];
  const int r0 = blockIdx.x * 16, t = threadIdx.x;
  for (int i = t; i < 4096; i += 256) {
    int r = i >> 8, k = i & 255;
    float s = b1[k];
#pragma unroll
    for (int p = 0; p < 16; ++p) s += h1p[(size_t)p * 131072 + (size_t)(r0 + r) * 256 + k];
    h1s[r * HS + k] = s;
    w2s[i] = w2[i];
  }
  __syncthreads();
  const int j = t & 15, r = t >> 4;
  float acc = b2[j];
#pragma unroll 4
  for (int k4 = 0; k4 < 64; ++k4) {
    float4 hv = *(const float4*)&h1s[r * HS + 4 * k4];
    float h0 = fmaxf(hv.x, 0.f), h1v = fmaxf(hv.y, 0.f);
    float h2v = fmaxf(hv.z, 0.f), h3 = fmaxf(hv.w, 0.f);
    acc += h0 * w2s[(4 * k4 + 0) * 16 + j];
    acc += h1v * w2s[(4 * k4 + 1) * 16 + j];
    acc += h2v * w2s[(4 * k4 + 2) * 16 + j];
    acc += h3 * w2s[(4 * k4 + 3) * 16 + j];
  }
  float v = fmaxf(acc, 0.f) * sw[j];
#pragma unroll
  for (int off = 8; off; off >>= 1) v += __shfl_xor(v, off, 16);
  if (j == 0) out[r0 + r] = v + sb[0];
}

// =================== launcher ===================
extern "C" void kernel_launch(void* const* d_in, const int* in_sizes, int n_in,
                              void* d_out, int out_size, void* d_ws, size_t ws_size,
                              hipStream_t stream) {
  const float* x_q = (const float*)d_in[0];
  const float* x_c = (const float*)d_in[1];
  const int* edge_q = (const int*)d_in[2];
  const int* edge_c = (const int*)d_in[3];
  const float* gw1 = (const float*)d_in[4];
  const float* gb1 = (const float*)d_in[5];
  const float* gw2 = (const float*)d_in[6];
  const float* gb2 = (const float*)d_in[7];
  const float* gw3 = (const float*)d_in[8];
  const float* gb3 = (const float*)d_in[9];
  const float* cw1 = (const float*)d_in[10];
  const float* cb1 = (const float*)d_in[11];
  const float* cw2 = (const float*)d_in[12];
  const float* cb2 = (const float*)d_in[13];
  const float* cw3 = (const float*)d_in[14];
  const float* cb3 = (const float*)d_in[15];
  const float* lw1 = (const float*)d_in[16];
  const float* lb1 = (const float*)d_in[17];
  const float* lw2 = (const float*)d_in[18];
  const float* lb2 = (const float*)d_in[19];
  const float* swt = (const float*)d_in[20];
  const float* sbs = (const float*)d_in[21];
  float* ws = (float*)d_ws;

  const size_t o_f1q = 65536;
  const size_t o_f2q = o_f1q + 2097152;
  const size_t o_f3q = o_f2q + 1048576;
  const size_t o_f1c = o_f3q + 524288;
  const size_t o_f2c = o_f1c + 2097152;
  const size_t o_f3c = o_f2c + 1048576;
  const size_t o_sims = o_f3c + 524288;
  const size_t o_pm1 = o_sims + 6291456;
  const size_t o_pm2 = o_pm1 + 6291456;
  const size_t o_wT = o_pm2 + 3145728;
  const size_t o_w2p = o_wT + 786432;
  const size_t o_w3p = o_w2p + 8192;
  const size_t o_feat = o_sims;
  const size_t o_h1p = o_f1q;

  u16* f1q = (u16*)(ws + o_f1q); u16* f2q = (u16*)(ws + o_f2q); u16* f3q = (u16*)(ws + o_f3q);
  u16* f1c = (u16*)(ws + o_f1c); u16* f2c = (u16*)(ws + o_f2c); u16* f3c = (u16*)(ws + o_f3c);
  u16* pm1 = (u16*)(ws + o_pm1);
  u16* wT = (u16*)(ws + o_wT);
  u16* w2p = (u16*)(ws + o_w2p);
  u16* w3p = (u16*)(ws + o_w3p);
  u16* feat = (u16*)(ws + o_feat);
  float* h1p = ws + o_h1p;

  prep_kernel<<<580, 256, 0, stream>>>(lw1, cw2, cw3, wT, w2p, w3p);

  gcn_fused<<<dim3(B, 2), 256, 0, stream>>>(x_q, x_c, gw1, gb1, gw2, gb2, gw3, gb3,
                                            edge_q, edge_c, f1q, f1c, f2q, f2c, f3q, f3c);

  simconv1<<<dim3(B, 3, 2), 256, 0, stream>>>(f1q, f1c, f2q, f2c, f3q, f3c, cw1, cb1, pm1);

  conv23_mfma<<<dim3(B, 3), 256, 0, stream>>>(pm1, w2p, cb2, w3p, cb3, feat);

  lin1_mfma<<<dim3(8, 4, 16), 256, 0, stream>>>(feat, wT, h1p);
  head_kernel<<<32, 256, 0, stream>>>(h1p, lb1, lw2, lb2, swt, sbs, (float*)d_out);
}

// Round 18
// 121.367 us; speedup vs baseline: 1.2489x; 1.2489x over previous
//
#include <hip/hip_runtime.h>
#include <hip/hip_bf16.h>

constexpr int B = 512, N = 64, E = 512, NE = B * E;

typedef __attribute__((ext_vector_type(8))) short bf8v;
typedef __attribute__((ext_vector_type(4))) float f32x4;
typedef unsigned short u16;

__device__ __forceinline__ u16 f2bf(float f) {
  unsigned u = __builtin_bit_cast(unsigned, f);
  u += 0x7FFFu + ((u >> 16) & 1u);
  return (u16)(u >> 16);
}

__device__ __forceinline__ int cmin(int a, int b) { return a < b ? a : b; }

// =================== fused 3-layer GCN via bf16 MFMA ===================
template <int DIN, int KP, int DOUT, bool STORE_NEXT>
__device__ __forceinline__ void gcn_layer_mfma(
    const u16* __restrict__ Ab, u16* __restrict__ Xb, u16* __restrict__ Hb,
    u16* __restrict__ Wb, const float* __restrict__ W,
    const float* __restrict__ bias, u16* __restrict__ fout, int g, int t) {
  for (int i = t; i < DOUT * KP; i += 256) {
    int c = i / KP, k = i % KP;
    u16 v = 0;
    if (k < DIN) v = f2bf(W[k * DOUT + c]);
    Wb[c * 72 + k] = v;
  }
  __syncthreads();
  const int w4 = t >> 6, lane = t & 63;
  const int r16 = lane & 15, kg = lane >> 4;
  constexpr int CT = DOUT / 16;
#pragma unroll
  for (int ct = 0; ct < CT; ++ct) {
    f32x4 acc = {0.f, 0.f, 0.f, 0.f};
#pragma unroll
    for (int ks = 0; ks < KP; ks += 32) {
      bf8v a = *(const bf8v*)&Xb[(w4 * 16 + r16) * 72 + ks + kg * 8];
      bf8v bb = *(const bf8v*)&Wb[(ct * 16 + r16) * 72 + ks + kg * 8];
      acc = __builtin_amdgcn_mfma_f32_16x16x32_bf16(a, bb, acc, 0, 0, 0);
    }
    ushort4 pk;
    pk.x = f2bf(acc[0]); pk.y = f2bf(acc[1]);
    pk.z = f2bf(acc[2]); pk.w = f2bf(acc[3]);
    *(ushort4*)&Hb[(ct * 16 + r16) * 72 + w4 * 16 + kg * 4] = pk;
  }
  __syncthreads();
#pragma unroll
  for (int ct = 0; ct < CT; ++ct) {
    f32x4 acc = {0.f, 0.f, 0.f, 0.f};
#pragma unroll
    for (int ks = 0; ks < 64; ks += 32) {
      bf8v a = *(const bf8v*)&Ab[(w4 * 16 + r16) * 72 + ks + kg * 8];
      bf8v bb = *(const bf8v*)&Hb[(ct * 16 + r16) * 72 + ks + kg * 8];
      acc = __builtin_amdgcn_mfma_f32_16x16x32_bf16(a, bb, acc, 0, 0, 0);
    }
    const int c = ct * 16 + r16;
    const float bv = bias[c];
#pragma unroll
    for (int j = 0; j < 4; ++j) {
      float st = acc[j] + bv;
      const int d = w4 * 16 + kg * 4 + j;
      fout[(size_t)g * N * DOUT + (size_t)d * DOUT + c] = f2bf(st);
      if (STORE_NEXT) Xb[d * 72 + c] = f2bf(fmaxf(st, 0.f));
    }
  }
  __syncthreads();
}

__global__ __launch_bounds__(256) void gcn_fused(
    const float* __restrict__ xq, const float* __restrict__ xc,
    const float* __restrict__ W1, const float* __restrict__ b1,
    const float* __restrict__ W2, const float* __restrict__ b2,
    const float* __restrict__ W3, const float* __restrict__ b3,
    const int* __restrict__ eq, const int* __restrict__ ec,
    u16* __restrict__ f1q, u16* __restrict__ f1c,
    u16* __restrict__ f2q, u16* __restrict__ f2c,
    u16* __restrict__ f3q, u16* __restrict__ f3c) {
  __shared__ __align__(16) float Af[64 * 68];   // later aliased as Wb
  __shared__ __align__(16) u16 Ab[64 * 72];
  __shared__ __align__(16) u16 Xb[64 * 72];
  __shared__ __align__(16) u16 Hb[64 * 72];
  __shared__ float dl[N];
  __shared__ int cnt[N];
  u16* Wb = (u16*)Af;
  const int g = blockIdx.x, t = threadIdx.x;
  const float* x = blockIdx.y ? xc : xq;
  const int* edges = blockIdx.y ? ec : eq;
  u16* o1 = blockIdx.y ? f1c : f1q;
  u16* o2 = blockIdx.y ? f2c : f2q;
  u16* o3 = blockIdx.y ? f3c : f3q;
  for (int i = t; i < 64 * 32; i += 256) {
    int n = i >> 5, k = i & 31;
    u16 v = 0;
    if (k < 16) v = f2bf(x[(size_t)g * 1024 + n * 16 + k]);
    Xb[n * 72 + k] = v;
  }
  for (int i = t; i < 64 * 68; i += 256) Af[i] = 0.f;
  if (t < N) cnt[t] = 1;
  __syncthreads();
  const int* srcp = edges + (size_t)g * E;
  const int* dstp = edges + NE + (size_t)g * E;
  for (int j = t; j < E; j += 256) atomicAdd(&cnt[dstp[j] & 63], 1);
  __syncthreads();
  if (t < N) dl[t] = rsqrtf((float)cnt[t]);
  __syncthreads();
  for (int j = t; j < E; j += 256) {
    int s = srcp[j] & 63, d = dstp[j] & 63;
    atomicAdd(&Af[d * 68 + s], dl[s] * dl[d]);
  }
  if (t < N) atomicAdd(&Af[t * 68 + t], dl[t] * dl[t]);
  __syncthreads();
  for (int i = t; i < 4096; i += 256) {
    int d = i >> 6, s = i & 63;
    Ab[d * 72 + s] = f2bf(Af[d * 68 + s]);
  }
  __syncthreads();
  gcn_layer_mfma<16, 32, 64, true>(Ab, Xb, Hb, Wb, W1, b1, o1, g, t);
  gcn_layer_mfma<64, 64, 32, true>(Ab, Xb, Hb, Wb, W2, b2, o2, g, t);
  gcn_layer_mfma<32, 32, 16, false>(Ab, Xb, Hb, Wb, W3, b3, o3, g, t);
}

// =================== fused sim (bf16 MFMA) + conv1 (fp32 VALU, oc-pairs) ===================
__global__ __launch_bounds__(256, 4) void simconv1(
    const u16* __restrict__ f1q, const u16* __restrict__ f1c,
    const u16* __restrict__ f2q, const u16* __restrict__ f2c,
    const u16* __restrict__ f3q, const u16* __restrict__ f3c,
    const float* __restrict__ w, const float* __restrict__ bias,
    u16* __restrict__ out) {
  constexpr int PS = 68, QS = 72;
  __shared__ __align__(16) u16 Qs[64 * QS];
  __shared__ __align__(16) u16 Cs[64 * QS];
  __shared__ __align__(16) float simp[68 * 68];
  __shared__ float wls[25 * 8];  // [tap][oc]
  __shared__ float bls[8];
  const int b = blockIdx.x, m = blockIdx.y, t = threadIdx.x;
  for (int i = t; i < 68 * 68; i += 256) simp[i] = 0.f;
  if (t < 200) {
    int oc = t / 25, tap = t % 25;
    wls[tap * 8 + oc] = w[m * 200 + t];
  }
  if (t < 8) bls[t] = bias[m * 8 + t];
  const u16* fq = (m == 0) ? f1q : (m == 1) ? f2q : f3q;
  const u16* fc = (m == 0) ? f1c : (m == 1) ? f2c : f3c;
  const int D = 64 >> m;
  const int SEG = D >> 3;
  for (int i = t; i < 64 * SEG; i += 256) {
    int n = i / SEG, s = i - n * SEG;
    *(uint4*)&Qs[n * QS + s * 8] = *(const uint4*)&fq[(size_t)b * 64 * D + n * D + s * 8];
    *(uint4*)&Cs[n * QS + s * 8] = *(const uint4*)&fc[(size_t)b * 64 * D + n * D + s * 8];
  }
  if (m == 2 && t < 128) {
    int n = t >> 1, s = t & 1;
    uint4 z = {0u, 0u, 0u, 0u};
    *(uint4*)&Qs[n * QS + 16 + s * 8] = z;
    *(uint4*)&Cs[n * QS + 16 + s * 8] = z;
  }
  __syncthreads();
  const int w4 = t >> 6, lane = t & 63;
  const int r16 = lane & 15, kg = lane >> 4;
  const int Kpad = (m == 0) ? 64 : 32;
#pragma unroll 1
  for (int ct = 0; ct < 4; ++ct) {
    f32x4 acc = {0.f, 0.f, 0.f, 0.f};
    for (int ks = 0; ks < Kpad; ks += 32) {
      bf8v a = *(const bf8v*)&Qs[(w4 * 16 + r16) * QS + ks + kg * 8];
      bf8v bb = *(const bf8v*)&Cs[(ct * 16 + r16) * QS + ks + kg * 8];
      acc = __builtin_amdgcn_mfma_f32_16x16x32_bf16(a, bb, acc, 0, 0, 0);
    }
#pragma unroll
    for (int j = 0; j < 4; ++j)
      simp[(w4 * 16 + kg * 4 + j + 2) * PS + ct * 16 + r16 + 2] = acc[j];
  }
  __syncthreads();
  const int gy = t >> 4, gx = t & 15;
  float pr[8][8];
#pragma unroll
  for (int yy = 0; yy < 8; ++yy) {
    float4 a = *(const float4*)&simp[(4 * gy + yy) * PS + 4 * gx];
    float4 bb = *(const float4*)&simp[(4 * gy + yy) * PS + 4 * gx + 4];
    pr[yy][0] = a.x; pr[yy][1] = a.y; pr[yy][2] = a.z; pr[yy][3] = a.w;
    pr[yy][4] = bb.x; pr[yy][5] = bb.y; pr[yy][6] = bb.z; pr[yy][7] = bb.w;
  }
  u16* op = out + (size_t)(b * 3 + m) * 8192;
#pragma unroll 1
  for (int p2 = 0; p2 < 4; ++p2) {
    float acc[2][16];
#pragma unroll
    for (int p = 0; p < 16; ++p) { acc[0][p] = 0.f; acc[1][p] = 0.f; }
#pragma unroll
    for (int ky = 0; ky < 5; ++ky)
#pragma unroll
      for (int kx = 0; kx < 5; ++kx) {
        float2 wv = *(const float2*)&wls[(ky * 5 + kx) * 8 + p2 * 2];
#pragma unroll
        for (int dy = 0; dy < 4; ++dy)
#pragma unroll
          for (int dx = 0; dx < 4; ++dx) {
            float rv = pr[ky + dy][kx + dx];
            acc[0][dy * 4 + dx] += rv * wv.x;
            acc[1][dy * 4 + dx] += rv * wv.y;
          }
      }
    float b0 = bls[p2 * 2], b1 = bls[p2 * 2 + 1];
#pragma unroll
    for (int ay = 0; ay < 2; ++ay)
#pragma unroll
      for (int ax = 0; ax < 2; ++ax) {
        float v0 = fmaxf(fmaxf(acc[0][(2 * ay) * 4 + 2 * ax], acc[0][(2 * ay) * 4 + 2 * ax + 1]),
                         fmaxf(acc[0][(2 * ay + 1) * 4 + 2 * ax], acc[0][(2 * ay + 1) * 4 + 2 * ax + 1]));
        float v1 = fmaxf(fmaxf(acc[1][(2 * ay) * 4 + 2 * ax], acc[1][(2 * ay) * 4 + 2 * ax + 1]),
                         fmaxf(acc[1][(2 * ay + 1) * 4 + 2 * ax], acc[1][(2 * ay + 1) * 4 + 2 * ax + 1]));
        v0 = fmaxf(v0 + b0, 0.f);
        v1 = fmaxf(v1 + b1, 0.f);
        unsigned pack = (unsigned)f2bf(v0) | ((unsigned)f2bf(v1) << 16);
        *(unsigned*)&op[(size_t)(((2 * gy + ay) * 32) + (2 * gx + ax)) * 8 + p2 * 2] = pack;
      }
  }
}

// =================== prep: wcvt (blocks 0..383) + wprep (blocks 384..579) ===================
__global__ __launch_bounds__(256) void prep_kernel(
    const float* __restrict__ lw1, const float* __restrict__ cw2,
    const float* __restrict__ cw3, u16* __restrict__ wT,
    u16* __restrict__ w2p, u16* __restrict__ w3p) {
  const int t = threadIdx.x;
  if (blockIdx.x < 384) {
    __shared__ float tile[64][65];
    const int k0 = (blockIdx.x % 96) * 64, c0 = (blockIdx.x / 96) * 64;
    for (int i = t; i < 4096; i += 256) {
      int r = i >> 6, c = i & 63;
      tile[r][c] = lw1[(size_t)(k0 + r) * 256 + c0 + c];
    }
    __syncthreads();
    for (int i = t; i < 4096; i += 256) {
      int c = i >> 6, k = i & 63;
      wT[(size_t)(c0 + c) * 6144 + k0 + k] = f2bf(tile[k][c]);
    }
    return;
  }
  int i = (blockIdx.x - 384) * 256 + t;
  if (i < 3 * 7 * 16 * 40) {
    int m = i / 4480, r = i % 4480;
    int k = r % 40, rest = r / 40, oc = rest & 15, st = rest >> 4;
    u16 v = 0;
    if (k < 32) {
      int sl = k >> 3, ci = k & 7, tap = st * 4 + sl;
      if (tap < 25) v = f2bf(cw2[((size_t)(m * 16 + oc) * 8 + ci) * 25 + tap]);
    }
    w2p[i] = v;
  }
  if (i < 3 * 26 * 16 * 40) {
    int m = i / 16640, r = i % 16640;
    int k = r % 40, rest = r / 40, oc16 = rest & 15, sthalf = rest >> 4;
    int half = sthalf & 1, st = sthalf >> 1;
    u16 v = 0;
    if (k < 32) {
      int sl = k >> 4, ci = k & 15, tap = st * 2 + sl;
      int oc = half * 16 + oc16;
      if (tap < 25) v = f2bf(cw3[((size_t)(m * 32 + oc) * 16 + ci) * 25 + tap]);
    }
    w3p[i] = v;
  }
}

// =================== conv2+conv3 fused ===================
__global__ __launch_bounds__(256) void conv23_mfma(
    const u16* __restrict__ in, const u16* __restrict__ w2p,
    const float* __restrict__ cb2, const u16* __restrict__ w3p,
    const float* __restrict__ cb3, u16* __restrict__ feat) {
  constexpr int PW2 = 36, PW3 = 20, BS = 40;
  __shared__ __align__(16) u16 uni[16640];
  __shared__ __align__(16) u16 p2s[PW3 * PW3 * 16];
  __shared__ float bls2[16];
  __shared__ float bls3[32];
  const int b = blockIdx.x, m = blockIdx.y, t = threadIdx.x;
  u16* ins2 = uni;
  u16* w2ls = uni + 10368;
  const size_t ibase = (size_t)(b * 3 + m) * 8192;
  for (int i = t; i < PW2 * PW2; i += 256) {
    int y = i / PW2, x = i % PW2;
    uint4 v = {0u, 0u, 0u, 0u};
    if (y >= 2 && y < 34 && x >= 2 && x < 34)
      v = *(const uint4*)&in[ibase + (size_t)((y - 2) * 32 + (x - 2)) * 8];
    *(uint4*)&ins2[i * 8] = v;
  }
  {
    const u16* wsrc = w2p + m * 4480;
    for (int i = t; i < 560; i += 256) *(uint4*)&w2ls[i * 8] = *(const uint4*)&wsrc[i * 8];
  }
  {
    uint4 z = {0u, 0u, 0u, 0u};
    for (int i = t; i < 800; i += 256) *(uint4*)&p2s[i * 8] = z;
  }
  if (t < 16) bls2[t] = cb2[m * 16 + t];
  if (t >= 32 && t < 64) bls3[t - 32] = cb3[m * 32 + (t - 32)];
  __syncthreads();
  const int wv = t >> 6, lane = t & 63;
  const int oc = lane & 15, g = lane >> 4;
  {
    const int xt = wv & 1, ypb = wv >> 1;
    const int x = xt * 16 + oc;
    __builtin_amdgcn_s_setprio(1);
#pragma unroll 1
    for (int grp = 0; grp < 2; ++grp) {
      f32x4 acc[4][2];
#pragma unroll
      for (int i = 0; i < 4; ++i) {
        acc[i][0] = (f32x4){0.f, 0.f, 0.f, 0.f};
        acc[i][1] = (f32x4){0.f, 0.f, 0.f, 0.f};
      }
#pragma unroll
      for (int st = 0; st < 7; ++st) {
        bf8v bvv = *(const bf8v*)&w2ls[(st * 16 + oc) * BS + g * 8];
        const int c0 = cmin(st * 4 + 0, 24), c1 = cmin(st * 4 + 1, 24);
        const int c2 = cmin(st * 4 + 2, 24), c3 = cmin(st * 4 + 3, 24);
        const int k0 = (c0 / 5) * PW2 + c0 % 5, k1 = (c1 / 5) * PW2 + c1 % 5;
        const int k2 = (c2 / 5) * PW2 + c2 % 5, k3 = (c3 / 5) * PW2 + c3 % 5;
        const int koff = (g == 0) ? k0 : (g == 1) ? k1 : (g == 2) ? k2 : k3;
#pragma unroll
        for (int i = 0; i < 4; ++i) {
          const int y0 = 2 * ypb + 4 * (grp * 4 + i);
          const int abase = (y0 * PW2 + x + koff) * 8;
          bf8v a0 = *(const bf8v*)&ins2[abase];
          acc[i][0] = __builtin_amdgcn_mfma_f32_16x16x32_bf16(a0, bvv, acc[i][0], 0, 0, 0);
          bf8v a1 = *(const bf8v*)&ins2[abase + PW2 * 8];
          acc[i][1] = __builtin_amdgcn_mfma_f32_16x16x32_bf16(a1, bvv, acc[i][1], 0, 0, 0);
        }
      }
      const float bb = bls2[oc];
#pragma unroll
      for (int i = 0; i < 4; ++i) {
        const int yp = ypb + 2 * (grp * 4 + i);
        const float v0 = fmaxf(fmaxf(fmaxf(acc[i][0][0], acc[i][0][1]),
                                     fmaxf(acc[i][1][0], acc[i][1][1])) + bb, 0.f);
        const float v1 = fmaxf(fmaxf(fmaxf(acc[i][0][2], acc[i][0][3]),
                                     fmaxf(acc[i][1][2], acc[i][1][3])) + bb, 0.f);
        const int px = xt * 8 + 2 * g;
        p2s[((yp + 2) * PW3 + (px + 2)) * 16 + oc] = f2bf(v0);
        p2s[((yp + 2) * PW3 + (px + 3)) * 16 + oc] = f2bf(v1);
      }
    }
    __builtin_amdgcn_s_setprio(0);
  }
  __syncthreads();
  {
    const u16* wsrc = w3p + m * 16640;
    for (int i = t; i < 2080; i += 256) *(uint4*)&uni[i * 8] = *(const uint4*)&wsrc[i * 8];
  }
  __syncthreads();
  {
    const int sl = g >> 1, ch = (g & 1) * 8;
    const int half = wv & 1, ypb = wv >> 1;
    u16* fb = feat + (size_t)b * 6144 + m * 2048;
    f32x4 acc[4][2];
#pragma unroll
    for (int i = 0; i < 4; ++i) {
      acc[i][0] = (f32x4){0.f, 0.f, 0.f, 0.f};
      acc[i][1] = (f32x4){0.f, 0.f, 0.f, 0.f};
    }
    __builtin_amdgcn_s_setprio(1);
#pragma unroll
    for (int st = 0; st < 13; ++st) {
      bf8v bvv = *(const bf8v*)&uni[(size_t)((st * 2 + half) * 16 + oc) * BS + g * 8];
      const int c0 = cmin(st * 2 + 0, 24), c1 = cmin(st * 2 + 1, 24);
      const int k0 = (c0 / 5) * PW3 + c0 % 5, k1 = (c1 / 5) * PW3 + c1 % 5;
      const int koff = sl ? k1 : k0;
#pragma unroll
      for (int i = 0; i < 4; ++i) {
        const int y0 = 2 * ypb + 4 * i;
        const int abase = (y0 * PW3 + oc + koff) * 16 + ch;
        bf8v a0 = *(const bf8v*)&p2s[abase];
        acc[i][0] = __builtin_amdgcn_mfma_f32_16x16x32_bf16(a0, bvv, acc[i][0], 0, 0, 0);
        bf8v a1 = *(const bf8v*)&p2s[abase + PW3 * 16];
        acc[i][1] = __builtin_amdgcn_mfma_f32_16x16x32_bf16(a1, bvv, acc[i][1], 0, 0, 0);
      }
    }
    __builtin_amdgcn_s_setprio(0);
    const int ocg = half * 16 + oc;
    const float bb = bls3[ocg];
#pragma unroll
    for (int i = 0; i < 4; ++i) {
      const int yp = ypb + 2 * i;
      const float v0 = fmaxf(fmaxf(fmaxf(acc[i][0][0], acc[i][0][1]),
                                   fmaxf(acc[i][1][0], acc[i][1][1])) + bb, 0.f);
      const float v1 = fmaxf(fmaxf(fmaxf(acc[i][0][2], acc[i][0][3]),
                                   fmaxf(acc[i][1][2], acc[i][1][3])) + bb, 0.f);
      unsigned pack = (unsigned)f2bf(v0) | ((unsigned)f2bf(v1) << 16);
      *(unsigned*)&fb[ocg * 64 + yp * 8 + 2 * g] = pack;
    }
  }
}

// =================== lin1: bf16 MFMA GEMM ===================
__global__ __launch_bounds__(256) void lin1_mfma(const u16* __restrict__ feat,
                                                 const u16* __restrict__ wT,
                                                 float* __restrict__ h1p) {
  constexpr int AS = 72;
  __shared__ __align__(16) u16 As[64 * AS];
  __shared__ __align__(16) u16 Bs[64 * AS];
  const int r0 = blockIdx.x * 64, c0 = blockIdx.y * 64, kb = blockIdx.z * 384;
  const int t = threadIdx.x;
  const int w = t >> 6, lane = t & 63;
  const int row16 = lane & 15, kg = lane >> 4;
  f32x4 acc[4] = {{0.f, 0.f, 0.f, 0.f}, {0.f, 0.f, 0.f, 0.f},
                  {0.f, 0.f, 0.f, 0.f}, {0.f, 0.f, 0.f, 0.f}};
  const int lr = t >> 2, lk = (t & 3) * 16;
#pragma unroll 1
  for (int st = 0; st < 6; ++st) {
    __syncthreads();
    const int ks = kb + st * 64;
    {
      const u16* srcA = feat + (size_t)(r0 + lr) * 6144 + ks + lk;
      uint4 a0 = *(const uint4*)srcA;
      uint4 a1 = *(const uint4*)(srcA + 8);
      *(uint4*)&As[lr * AS + lk] = a0;
      *(uint4*)&As[lr * AS + lk + 8] = a1;
      const u16* srcB = wT + (size_t)(c0 + lr) * 6144 + ks + lk;
      uint4 b0 = *(const uint4*)srcB;
      uint4 b1 = *(const uint4*)(srcB + 8);
      *(uint4*)&Bs[lr * AS + lk] = b0;
      *(uint4*)&Bs[lr * AS + lk + 8] = b1;
    }
    __syncthreads();
#pragma unroll
    for (int kk = 0; kk < 2; ++kk) {
      bf8v a = *(const bf8v*)&As[(w * 16 + row16) * AS + kk * 32 + kg * 8];
#pragma unroll
      for (int ct = 0; ct < 4; ++ct) {
        bf8v bb = *(const bf8v*)&Bs[(ct * 16 + row16) * AS + kk * 32 + kg * 8];
        acc[ct] = __builtin_amdgcn_mfma_f32_16x16x32_bf16(a, bb, acc[ct], 0, 0, 0);
      }
    }
  }
  float* out = h1p + (size_t)blockIdx.z * 131072;
#pragma unroll
  for (int ct = 0; ct < 4; ++ct)
#pragma unroll
    for (int j = 0; j < 4; ++j)
      out[(size_t)(r0 + w * 16 + kg * 4 + j) * 256 + c0 + ct * 16 + row16] = acc[ct][j];
}

// =================== head ===================
__global__ __launch_bounds__(256) void head_kernel(
    const float* __restrict__ h1p, const float* __restrict__ b1,
    const float* __restrict__ w2, const float* __restrict__ b2,
    const float* __restrict__ sw, const float* __restrict__ sb,
    float* __restrict__ out) {
  constexpr int HS = 260;
  __shared__ __align__(16) float h1s[16 * HS];
  __shared__ __align__(16) float w2s[256 * 16];
  const int r0 = blockIdx.x * 16, t = threadIdx.x;
  for (int i = t; i < 4096; i += 256) {
    int r = i >> 8, k = i & 255;
    float s = b1[k];
#pragma unroll
    for (int p = 0; p < 16; ++p) s += h1p[(size_t)p * 131072 + (size_t)(r0 + r) * 256 + k];
    h1s[r * HS + k] = s;
    w2s[i] = w2[i];
  }
  __syncthreads();
  const int j = t & 15, r = t >> 4;
  float acc = b2[j];
#pragma unroll 4
  for (int k4 = 0; k4 < 64; ++k4) {
    float4 hv = *(const float4*)&h1s[r * HS + 4 * k4];
    float h0 = fmaxf(hv.x, 0.f), h1v = fmaxf(hv.y, 0.f);
    float h2v = fmaxf(hv.z, 0.f), h3 = fmaxf(hv.w, 0.f);
    acc += h0 * w2s[(4 * k4 + 0) * 16 + j];
    acc += h1v * w2s[(4 * k4 + 1) * 16 + j];
    acc += h2v * w2s[(4 * k4 + 2) * 16 + j];
    acc += h3 * w2s[(4 * k4 + 3) * 16 + j];
  }
  float v = fmaxf(acc, 0.f) * sw[j];
#pragma unroll
  for (int off = 8; off; off >>= 1) v += __shfl_xor(v, off, 16);
  if (j == 0) out[r0 + r] = v + sb[0];
}

// =================== launcher ===================
extern "C" void kernel_launch(void* const* d_in, const int* in_sizes, int n_in,
                              void* d_out, int out_size, void* d_ws, size_t ws_size,
                              hipStream_t stream) {
  const float* x_q = (const float*)d_in[0];
  const float* x_c = (const float*)d_in[1];
  const int* edge_q = (const int*)d_in[2];
  const int* edge_c = (const int*)d_in[3];
  const float* gw1 = (const float*)d_in[4];
  const float* gb1 = (const float*)d_in[5];
  const float* gw2 = (const float*)d_in[6];
  const float* gb2 = (const float*)d_in[7];
  const float* gw3 = (const float*)d_in[8];
  const float* gb3 = (const float*)d_in[9];
  const float* cw1 = (const float*)d_in[10];
  const float* cb1 = (const float*)d_in[11];
  const float* cw2 = (const float*)d_in[12];
  const float* cb2 = (const float*)d_in[13];
  const float* cw3 = (const float*)d_in[14];
  const float* cb3 = (const float*)d_in[15];
  const float* lw1 = (const float*)d_in[16];
  const float* lb1 = (const float*)d_in[17];
  const float* lw2 = (const float*)d_in[18];
  const float* lb2 = (const float*)d_in[19];
  const float* swt = (const float*)d_in[20];
  const float* sbs = (const float*)d_in[21];
  float* ws = (float*)d_ws;

  const size_t o_f1q = 65536;
  const size_t o_f2q = o_f1q + 2097152;
  const size_t o_f3q = o_f2q + 1048576;
  const size_t o_f1c = o_f3q + 524288;
  const size_t o_f2c = o_f1c + 2097152;
  const size_t o_f3c = o_f2c + 1048576;
  const size_t o_sims = o_f3c + 524288;
  const size_t o_pm1 = o_sims + 6291456;
  const size_t o_pm2 = o_pm1 + 6291456;
  const size_t o_wT = o_pm2 + 3145728;
  const size_t o_w2p = o_wT + 786432;
  const size_t o_w3p = o_w2p + 8192;
  const size_t o_feat = o_sims;
  const size_t o_h1p = o_f1q;

  u16* f1q = (u16*)(ws + o_f1q); u16* f2q = (u16*)(ws + o_f2q); u16* f3q = (u16*)(ws + o_f3q);
  u16* f1c = (u16*)(ws + o_f1c); u16* f2c = (u16*)(ws + o_f2c); u16* f3c = (u16*)(ws + o_f3c);
  u16* pm1 = (u16*)(ws + o_pm1);
  u16* wT = (u16*)(ws + o_wT);
  u16* w2p = (u16*)(ws + o_w2p);
  u16* w3p = (u16*)(ws + o_w3p);
  u16* feat = (u16*)(ws + o_feat);
  float* h1p = ws + o_h1p;

  prep_kernel<<<580, 256, 0, stream>>>(lw1, cw2, cw3, wT, w2p, w3p);

  gcn_fused<<<dim3(B, 2), 256, 0, stream>>>(x_q, x_c, gw1, gb1, gw2, gb2, gw3, gb3,
                                            edge_q, edge_c, f1q, f1c, f2q, f2c, f3q, f3c);

  simconv1<<<dim3(B, 3), 256, 0, stream>>>(f1q, f1c, f2q, f2c, f3q, f3c, cw1, cb1, pm1);

  conv23_mfma<<<dim3(B, 3), 256, 0, stream>>>(pm1, w2p, cb2, w3p, cb3, feat);

  lin1_mfma<<<dim3(8, 4, 16), 256, 0, stream>>>(feat, wT, h1p);
  head_kernel<<<32, 256, 0, stream>>>(h1p, lb1, lw2, lb2, swt, sbs, (float*)d_out);
}

// Round 19
// 120.780 us; speedup vs baseline: 1.2550x; 1.0049x over previous
//
#include <hip/hip_runtime.h>
#include <hip/hip_bf16.h>

constexpr int B = 512, N = 64, E = 512, NE = B * E;

typedef __attribute__((ext_vector_type(8))) short bf8v;
typedef __attribute__((ext_vector_type(4))) float f32x4;
typedef unsigned short u16;

__device__ __forceinline__ u16 f2bf(float f) {
  unsigned u = __builtin_bit_cast(unsigned, f);
  u += 0x7FFFu + ((u >> 16) & 1u);
  return (u16)(u >> 16);
}
__device__ __forceinline__ float bflo(unsigned u) {
  return __builtin_bit_cast(float, u << 16);
}
__device__ __forceinline__ float bfhi(unsigned u) {
  return __builtin_bit_cast(float, u & 0xFFFF0000u);
}

__device__ __forceinline__ int cmin(int a, int b) { return a < b ? a : b; }

// =================== fused 3-layer GCN via bf16 MFMA (unchanged) ===================
template <int DIN, int KP, int DOUT, bool STORE_NEXT>
__device__ __forceinline__ void gcn_layer_mfma(
    const u16* __restrict__ Ab, u16* __restrict__ Xb, u16* __restrict__ Hb,
    u16* __restrict__ Wb, const float* __restrict__ W,
    const float* __restrict__ bias, u16* __restrict__ fout, int g, int t) {
  for (int i = t; i < DOUT * KP; i += 256) {
    int c = i / KP, k = i % KP;
    u16 v = 0;
    if (k < DIN) v = f2bf(W[k * DOUT + c]);
    Wb[c * 72 + k] = v;
  }
  __syncthreads();
  const int w4 = t >> 6, lane = t & 63;
  const int r16 = lane & 15, kg = lane >> 4;
  constexpr int CT = DOUT / 16;
#pragma unroll
  for (int ct = 0; ct < CT; ++ct) {
    f32x4 acc = {0.f, 0.f, 0.f, 0.f};
#pragma unroll
    for (int ks = 0; ks < KP; ks += 32) {
      bf8v a = *(const bf8v*)&Xb[(w4 * 16 + r16) * 72 + ks + kg * 8];
      bf8v bb = *(const bf8v*)&Wb[(ct * 16 + r16) * 72 + ks + kg * 8];
      acc = __builtin_amdgcn_mfma_f32_16x16x32_bf16(a, bb, acc, 0, 0, 0);
    }
    ushort4 pk;
    pk.x = f2bf(acc[0]); pk.y = f2bf(acc[1]);
    pk.z = f2bf(acc[2]); pk.w = f2bf(acc[3]);
    *(ushort4*)&Hb[(ct * 16 + r16) * 72 + w4 * 16 + kg * 4] = pk;
  }
  __syncthreads();
#pragma unroll
  for (int ct = 0; ct < CT; ++ct) {
    f32x4 acc = {0.f, 0.f, 0.f, 0.f};
#pragma unroll
    for (int ks = 0; ks < 64; ks += 32) {
      bf8v a = *(const bf8v*)&Ab[(w4 * 16 + r16) * 72 + ks + kg * 8];
      bf8v bb = *(const bf8v*)&Hb[(ct * 16 + r16) * 72 + ks + kg * 8];
      acc = __builtin_amdgcn_mfma_f32_16x16x32_bf16(a, bb, acc, 0, 0, 0);
    }
    const int c = ct * 16 + r16;
    const float bv = bias[c];
#pragma unroll
    for (int j = 0; j < 4; ++j) {
      float st = acc[j] + bv;
      const int d = w4 * 16 + kg * 4 + j;
      fout[(size_t)g * N * DOUT + (size_t)d * DOUT + c] = f2bf(st);
      if (STORE_NEXT) Xb[d * 72 + c] = f2bf(fmaxf(st, 0.f));
    }
  }
  __syncthreads();
}

__global__ __launch_bounds__(256) void gcn_fused(
    const float* __restrict__ xq, const float* __restrict__ xc,
    const float* __restrict__ W1, const float* __restrict__ b1,
    const float* __restrict__ W2, const float* __restrict__ b2,
    const float* __restrict__ W3, const float* __restrict__ b3,
    const int* __restrict__ eq, const int* __restrict__ ec,
    u16* __restrict__ f1q, u16* __restrict__ f1c,
    u16* __restrict__ f2q, u16* __restrict__ f2c,
    u16* __restrict__ f3q, u16* __restrict__ f3c) {
  __shared__ __align__(16) float Af[64 * 68];   // later aliased as Wb
  __shared__ __align__(16) u16 Ab[64 * 72];
  __shared__ __align__(16) u16 Xb[64 * 72];
  __shared__ __align__(16) u16 Hb[64 * 72];
  __shared__ float dl[N];
  __shared__ int cnt[N];
  u16* Wb = (u16*)Af;
  const int g = blockIdx.x, t = threadIdx.x;
  const float* x = blockIdx.y ? xc : xq;
  const int* edges = blockIdx.y ? ec : eq;
  u16* o1 = blockIdx.y ? f1c : f1q;
  u16* o2 = blockIdx.y ? f2c : f2q;
  u16* o3 = blockIdx.y ? f3c : f3q;
  for (int i = t; i < 64 * 32; i += 256) {
    int n = i >> 5, k = i & 31;
    u16 v = 0;
    if (k < 16) v = f2bf(x[(size_t)g * 1024 + n * 16 + k]);
    Xb[n * 72 + k] = v;
  }
  for (int i = t; i < 64 * 68; i += 256) Af[i] = 0.f;
  if (t < N) cnt[t] = 1;
  __syncthreads();
  const int* srcp = edges + (size_t)g * E;
  const int* dstp = edges + NE + (size_t)g * E;
  for (int j = t; j < E; j += 256) atomicAdd(&cnt[dstp[j] & 63], 1);
  __syncthreads();
  if (t < N) dl[t] = rsqrtf((float)cnt[t]);
  __syncthreads();
  for (int j = t; j < E; j += 256) {
    int s = srcp[j] & 63, d = dstp[j] & 63;
    atomicAdd(&Af[d * 68 + s], dl[s] * dl[d]);
  }
  if (t < N) atomicAdd(&Af[t * 68 + t], dl[t] * dl[t]);
  __syncthreads();
  for (int i = t; i < 4096; i += 256) {
    int d = i >> 6, s = i & 63;
    Ab[d * 72 + s] = f2bf(Af[d * 68 + s]);
  }
  __syncthreads();
  gcn_layer_mfma<16, 32, 64, true>(Ab, Xb, Hb, Wb, W1, b1, o1, g, t);
  gcn_layer_mfma<64, 64, 32, true>(Ab, Xb, Hb, Wb, W2, b2, o2, g, t);
  gcn_layer_mfma<32, 32, 16, false>(Ab, Xb, Hb, Wb, W3, b3, o3, g, t);
}

// =================== fused sim (bf16 MFMA) + conv1 (fp32 VALU), bf16 simp ===================
__global__ __launch_bounds__(256, 4) void simconv1(
    const u16* __restrict__ f1q, const u16* __restrict__ f1c,
    const u16* __restrict__ f2q, const u16* __restrict__ f2c,
    const u16* __restrict__ f3q, const u16* __restrict__ f3c,
    const float* __restrict__ w, const float* __restrict__ bias,
    u16* __restrict__ out) {
  constexpr int QS = 72, SB = 72;  // simp row stride (u16)
  __shared__ __align__(16) u16 Qs[64 * QS];
  __shared__ __align__(16) u16 Cs[64 * QS];
  __shared__ __align__(16) u16 simp[68 * SB];  // bf16 image, zero border
  __shared__ float wls[25 * 8];  // [tap][oc]
  __shared__ float bls[8];
  const int b = blockIdx.x, m = blockIdx.y, t = threadIdx.x;
  {
    uint4 z = {0u, 0u, 0u, 0u};
    for (int i = t; i < (68 * SB) / 8; i += 256) *(uint4*)&simp[i * 8] = z;
  }
  if (t < 200) {
    int oc = t / 25, tap = t % 25;
    wls[tap * 8 + oc] = w[m * 200 + t];
  }
  if (t < 8) bls[t] = bias[m * 8 + t];
  const u16* fq = (m == 0) ? f1q : (m == 1) ? f2q : f3q;
  const u16* fc = (m == 0) ? f1c : (m == 1) ? f2c : f3c;
  const int D = 64 >> m;
  const int SEG = D >> 3;
  for (int i = t; i < 64 * SEG; i += 256) {
    int n = i / SEG, s = i - n * SEG;
    *(uint4*)&Qs[n * QS + s * 8] = *(const uint4*)&fq[(size_t)b * 64 * D + n * D + s * 8];
    *(uint4*)&Cs[n * QS + s * 8] = *(const uint4*)&fc[(size_t)b * 64 * D + n * D + s * 8];
  }
  if (m == 2 && t < 128) {
    int n = t >> 1, s = t & 1;
    uint4 z = {0u, 0u, 0u, 0u};
    *(uint4*)&Qs[n * QS + 16 + s * 8] = z;
    *(uint4*)&Cs[n * QS + 16 + s * 8] = z;
  }
  __syncthreads();
  const int w4 = t >> 6, lane = t & 63;
  const int r16 = lane & 15, kg = lane >> 4;
  const int Kpad = (m == 0) ? 64 : 32;
#pragma unroll 1
  for (int ct = 0; ct < 4; ++ct) {
    f32x4 acc = {0.f, 0.f, 0.f, 0.f};
    for (int ks = 0; ks < Kpad; ks += 32) {
      bf8v a = *(const bf8v*)&Qs[(w4 * 16 + r16) * QS + ks + kg * 8];
      bf8v bb = *(const bf8v*)&Cs[(ct * 16 + r16) * QS + ks + kg * 8];
      acc = __builtin_amdgcn_mfma_f32_16x16x32_bf16(a, bb, acc, 0, 0, 0);
    }
#pragma unroll
    for (int j = 0; j < 4; ++j)
      simp[(w4 * 16 + kg * 4 + j + 2) * SB + ct * 16 + r16 + 2] = f2bf(acc[j]);
  }
  __syncthreads();
  const int gy = t >> 4, gx = t & 15;
  float pr[8][8];
#pragma unroll
  for (int yy = 0; yy < 8; ++yy) {
    uint2 a = *(const uint2*)&simp[(4 * gy + yy) * SB + 4 * gx];
    uint2 bq = *(const uint2*)&simp[(4 * gy + yy) * SB + 4 * gx + 4];
    pr[yy][0] = bflo(a.x); pr[yy][1] = bfhi(a.x);
    pr[yy][2] = bflo(a.y); pr[yy][3] = bfhi(a.y);
    pr[yy][4] = bflo(bq.x); pr[yy][5] = bfhi(bq.x);
    pr[yy][6] = bflo(bq.y); pr[yy][7] = bfhi(bq.y);
  }
  u16* op = out + (size_t)(b * 3 + m) * 8192;
#pragma unroll 1
  for (int p2 = 0; p2 < 4; ++p2) {
    float acc[2][16];
#pragma unroll
    for (int p = 0; p < 16; ++p) { acc[0][p] = 0.f; acc[1][p] = 0.f; }
#pragma unroll
    for (int ky = 0; ky < 5; ++ky)
#pragma unroll
      for (int kx = 0; kx < 5; ++kx) {
        float2 wv = *(const float2*)&wls[(ky * 5 + kx) * 8 + p2 * 2];
#pragma unroll
        for (int dy = 0; dy < 4; ++dy)
#pragma unroll
          for (int dx = 0; dx < 4; ++dx) {
            float rv = pr[ky + dy][kx + dx];
            acc[0][dy * 4 + dx] += rv * wv.x;
            acc[1][dy * 4 + dx] += rv * wv.y;
          }
      }
    float b0 = bls[p2 * 2], b1 = bls[p2 * 2 + 1];
#pragma unroll
    for (int ay = 0; ay < 2; ++ay)
#pragma unroll
      for (int ax = 0; ax < 2; ++ax) {
        float v0 = fmaxf(fmaxf(acc[0][(2 * ay) * 4 + 2 * ax], acc[0][(2 * ay) * 4 + 2 * ax + 1]),
                         fmaxf(acc[0][(2 * ay + 1) * 4 + 2 * ax], acc[0][(2 * ay + 1) * 4 + 2 * ax + 1]));
        float v1 = fmaxf(fmaxf(acc[1][(2 * ay) * 4 + 2 * ax], acc[1][(2 * ay) * 4 + 2 * ax + 1]),
                         fmaxf(acc[1][(2 * ay + 1) * 4 + 2 * ax], acc[1][(2 * ay + 1) * 4 + 2 * ax + 1]));
        v0 = fmaxf(v0 + b0, 0.f);
        v1 = fmaxf(v1 + b1, 0.f);
        unsigned pack = (unsigned)f2bf(v0) | ((unsigned)f2bf(v1) << 16);
        *(unsigned*)&op[(size_t)(((2 * gy + ay) * 32) + (2 * gx + ax)) * 8 + p2 * 2] = pack;
      }
  }
}

// =================== prep: wcvt (blocks 0..383) + wprep (blocks 384..579) ===================
__global__ __launch_bounds__(256) void prep_kernel(
    const float* __restrict__ lw1, const float* __restrict__ cw2,
    const float* __restrict__ cw3, u16* __restrict__ wT,
    u16* __restrict__ w2p, u16* __restrict__ w3p) {
  const int t = threadIdx.x;
  if (blockIdx.x < 384) {
    __shared__ float tile[64][65];
    const int k0 = (blockIdx.x % 96) * 64, c0 = (blockIdx.x / 96) * 64;
    for (int i = t; i < 4096; i += 256) {
      int r = i >> 6, c = i & 63;
      tile[r][c] = lw1[(size_t)(k0 + r) * 256 + c0 + c];
    }
    __syncthreads();
    for (int i = t; i < 4096; i += 256) {
      int c = i >> 6, k = i & 63;
      wT[(size_t)(c0 + c) * 6144 + k0 + k] = f2bf(tile[k][c]);
    }
    return;
  }
  int i = (blockIdx.x - 384) * 256 + t;
  if (i < 3 * 7 * 16 * 40) {
    int m = i / 4480, r = i % 4480;
    int k = r % 40, rest = r / 40, oc = rest & 15, st = rest >> 4;
    u16 v = 0;
    if (k < 32) {
      int sl = k >> 3, ci = k & 7, tap = st * 4 + sl;
      if (tap < 25) v = f2bf(cw2[((size_t)(m * 16 + oc) * 8 + ci) * 25 + tap]);
    }
    w2p[i] = v;
  }
  if (i < 3 * 26 * 16 * 40) {
    int m = i / 16640, r = i % 16640;
    int k = r % 40, rest = r / 40, oc16 = rest & 15, sthalf = rest >> 4;
    int half = sthalf & 1, st = sthalf >> 1;
    u16 v = 0;
    if (k < 32) {
      int sl = k >> 4, ci = k & 15, tap = st * 2 + sl;
      int oc = half * 16 + oc16;
      if (tap < 25) v = f2bf(cw3[((size_t)(m * 32 + oc) * 16 + ci) * 25 + tap]);
    }
    w3p[i] = v;
  }
}

// =================== conv2+conv3 fused (unchanged) ===================
__global__ __launch_bounds__(256) void conv23_mfma(
    const u16* __restrict__ in, const u16* __restrict__ w2p,
    const float* __restrict__ cb2, const u16* __restrict__ w3p,
    const float* __restrict__ cb3, u16* __restrict__ feat) {
  constexpr int PW2 = 36, PW3 = 20, BS = 40;
  __shared__ __align__(16) u16 uni[16640];
  __shared__ __align__(16) u16 p2s[PW3 * PW3 * 16];
  __shared__ float bls2[16];
  __shared__ float bls3[32];
  const int b = blockIdx.x, m = blockIdx.y, t = threadIdx.x;
  u16* ins2 = uni;
  u16* w2ls = uni + 10368;
  const size_t ibase = (size_t)(b * 3 + m) * 8192;
  for (int i = t; i < PW2 * PW2; i += 256) {
    int y = i / PW2, x = i % PW2;
    uint4 v = {0u, 0u, 0u, 0u};
    if (y >= 2 && y < 34 && x >= 2 && x < 34)
      v = *(const uint4*)&in[ibase + (size_t)((y - 2) * 32 + (x - 2)) * 8];
    *(uint4*)&ins2[i * 8] = v;
  }
  {
    const u16* wsrc = w2p + m * 4480;
    for (int i = t; i < 560; i += 256) *(uint4*)&w2ls[i * 8] = *(const uint4*)&wsrc[i * 8];
  }
  {
    uint4 z = {0u, 0u, 0u, 0u};
    for (int i = t; i < 800; i += 256) *(uint4*)&p2s[i * 8] = z;
  }
  if (t < 16) bls2[t] = cb2[m * 16 + t];
  if (t >= 32 && t < 64) bls3[t - 32] = cb3[m * 32 + (t - 32)];
  __syncthreads();
  const int wv = t >> 6, lane = t & 63;
  const int oc = lane & 15, g = lane >> 4;
  {
    const int xt = wv & 1, ypb = wv >> 1;
    const int x = xt * 16 + oc;
    __builtin_amdgcn_s_setprio(1);
#pragma unroll 1
    for (int grp = 0; grp < 2; ++grp) {
      f32x4 acc[4][2];
#pragma unroll
      for (int i = 0; i < 4; ++i) {
        acc[i][0] = (f32x4){0.f, 0.f, 0.f, 0.f};
        acc[i][1] = (f32x4){0.f, 0.f, 0.f, 0.f};
      }
#pragma unroll
      for (int st = 0; st < 7; ++st) {
        bf8v bvv = *(const bf8v*)&w2ls[(st * 16 + oc) * BS + g * 8];
        const int c0 = cmin(st * 4 + 0, 24), c1 = cmin(st * 4 + 1, 24);
        const int c2 = cmin(st * 4 + 2, 24), c3 = cmin(st * 4 + 3, 24);
        const int k0 = (c0 / 5) * PW2 + c0 % 5, k1 = (c1 / 5) * PW2 + c1 % 5;
        const int k2 = (c2 / 5) * PW2 + c2 % 5, k3 = (c3 / 5) * PW2 + c3 % 5;
        const int koff = (g == 0) ? k0 : (g == 1) ? k1 : (g == 2) ? k2 : k3;
#pragma unroll
        for (int i = 0; i < 4; ++i) {
          const int y0 = 2 * ypb + 4 * (grp * 4 + i);
          const int abase = (y0 * PW2 + x + koff) * 8;
          bf8v a0 = *(const bf8v*)&ins2[abase];
          acc[i][0] = __builtin_amdgcn_mfma_f32_16x16x32_bf16(a0, bvv, acc[i][0], 0, 0, 0);
          bf8v a1 = *(const bf8v*)&ins2[abase + PW2 * 8];
          acc[i][1] = __builtin_amdgcn_mfma_f32_16x16x32_bf16(a1, bvv, acc[i][1], 0, 0, 0);
        }
      }
      const float bb = bls2[oc];
#pragma unroll
      for (int i = 0; i < 4; ++i) {
        const int yp = ypb + 2 * (grp * 4 + i);
        const float v0 = fmaxf(fmaxf(fmaxf(acc[i][0][0], acc[i][0][1]),
                                     fmaxf(acc[i][1][0], acc[i][1][1])) + bb, 0.f);
        const float v1 = fmaxf(fmaxf(fmaxf(acc[i][0][2], acc[i][0][3]),
                                     fmaxf(acc[i][1][2], acc[i][1][3])) + bb, 0.f);
        const int px = xt * 8 + 2 * g;
        p2s[((yp + 2) * PW3 + (px + 2)) * 16 + oc] = f2bf(v0);
        p2s[((yp + 2) * PW3 + (px + 3)) * 16 + oc] = f2bf(v1);
      }
    }
    __builtin_amdgcn_s_setprio(0);
  }
  __syncthreads();
  {
    const u16* wsrc = w3p + m * 16640;
    for (int i = t; i < 2080; i += 256) *(uint4*)&uni[i * 8] = *(const uint4*)&wsrc[i * 8];
  }
  __syncthreads();
  {
    const int sl = g >> 1, ch = (g & 1) * 8;
    const int half = wv & 1, ypb = wv >> 1;
    u16* fb = feat + (size_t)b * 6144 + m * 2048;
    f32x4 acc[4][2];
#pragma unroll
    for (int i = 0; i < 4; ++i) {
      acc[i][0] = (f32x4){0.f, 0.f, 0.f, 0.f};
      acc[i][1] = (f32x4){0.f, 0.f, 0.f, 0.f};
    }
    __builtin_amdgcn_s_setprio(1);
#pragma unroll
    for (int st = 0; st < 13; ++st) {
      bf8v bvv = *(const bf8v*)&uni[(size_t)((st * 2 + half) * 16 + oc) * BS + g * 8];
      const int c0 = cmin(st * 2 + 0, 24), c1 = cmin(st * 2 + 1, 24);
      const int k0 = (c0 / 5) * PW3 + c0 % 5, k1 = (c1 / 5) * PW3 + c1 % 5;
      const int koff = sl ? k1 : k0;
#pragma unroll
      for (int i = 0; i < 4; ++i) {
        const int y0 = 2 * ypb + 4 * i;
        const int abase = (y0 * PW3 + oc + koff) * 16 + ch;
        bf8v a0 = *(const bf8v*)&p2s[abase];
        acc[i][0] = __builtin_amdgcn_mfma_f32_16x16x32_bf16(a0, bvv, acc[i][0], 0, 0, 0);
        bf8v a1 = *(const bf8v*)&p2s[abase + PW3 * 16];
        acc[i][1] = __builtin_amdgcn_mfma_f32_16x16x32_bf16(a1, bvv, acc[i][1], 0, 0, 0);
      }
    }
    __builtin_amdgcn_s_setprio(0);
    const int ocg = half * 16 + oc;
    const float bb = bls3[ocg];
#pragma unroll
    for (int i = 0; i < 4; ++i) {
      const int yp = ypb + 2 * i;
      const float v0 = fmaxf(fmaxf(fmaxf(acc[i][0][0], acc[i][0][1]),
                                   fmaxf(acc[i][1][0], acc[i][1][1])) + bb, 0.f);
      const float v1 = fmaxf(fmaxf(fmaxf(acc[i][0][2], acc[i][0][3]),
                                   fmaxf(acc[i][1][2], acc[i][1][3])) + bb, 0.f);
      unsigned pack = (unsigned)f2bf(v0) | ((unsigned)f2bf(v1) << 16);
      *(unsigned*)&fb[ocg * 64 + yp * 8 + 2 * g] = pack;
    }
  }
}

// =================== lin1: bf16 MFMA GEMM (unchanged) ===================
__global__ __launch_bounds__(256) void lin1_mfma(const u16* __restrict__ feat,
                                                 const u16* __restrict__ wT,
                                                 float* __restrict__ h1p) {
  constexpr int AS = 72;
  __shared__ __align__(16) u16 As[64 * AS];
  __shared__ __align__(16) u16 Bs[64 * AS];
  const int r0 = blockIdx.x * 64, c0 = blockIdx.y * 64, kb = blockIdx.z * 384;
  const int t = threadIdx.x;
  const int w = t >> 6, lane = t & 63;
  const int row16 = lane & 15, kg = lane >> 4;
  f32x4 acc[4] = {{0.f, 0.f, 0.f, 0.f}, {0.f, 0.f, 0.f, 0.f},
                  {0.f, 0.f, 0.f, 0.f}, {0.f, 0.f, 0.f, 0.f}};
  const int lr = t >> 2, lk = (t & 3) * 16;
#pragma unroll 1
  for (int st = 0; st < 6; ++st) {
    __syncthreads();
    const int ks = kb + st * 64;
    {
      const u16* srcA = feat + (size_t)(r0 + lr) * 6144 + ks + lk;
      uint4 a0 = *(const uint4*)srcA;
      uint4 a1 = *(const uint4*)(srcA + 8);
      *(uint4*)&As[lr * AS + lk] = a0;
      *(uint4*)&As[lr * AS + lk + 8] = a1;
      const u16* srcB = wT + (size_t)(c0 + lr) * 6144 + ks + lk;
      uint4 b0 = *(const uint4*)srcB;
      uint4 b1 = *(const uint4*)(srcB + 8);
      *(uint4*)&Bs[lr * AS + lk] = b0;
      *(uint4*)&Bs[lr * AS + lk + 8] = b1;
    }
    __syncthreads();
#pragma unroll
    for (int kk = 0; kk < 2; ++kk) {
      bf8v a = *(const bf8v*)&As[(w * 16 + row16) * AS + kk * 32 + kg * 8];
#pragma unroll
      for (int ct = 0; ct < 4; ++ct) {
        bf8v bb = *(const bf8v*)&Bs[(ct * 16 + row16) * AS + kk * 32 + kg * 8];
        acc[ct] = __builtin_amdgcn_mfma_f32_16x16x32_bf16(a, bb, acc[ct], 0, 0, 0);
      }
    }
  }
  float* out = h1p + (size_t)blockIdx.z * 131072;
#pragma unroll
  for (int ct = 0; ct < 4; ++ct)
#pragma unroll
    for (int j = 0; j < 4; ++j)
      out[(size_t)(r0 + w * 16 + kg * 4 + j) * 256 + c0 + ct * 16 + row16] = acc[ct][j];
}

// =================== head (unchanged) ===================
__global__ __launch_bounds__(256) void head_kernel(
    const float* __restrict__ h1p, const float* __restrict__ b1,
    const float* __restrict__ w2, const float* __restrict__ b2,
    const float* __restrict__ sw, const float* __restrict__ sb,
    float* __restrict__ out) {
  constexpr int HS = 260;
  __shared__ __align__(16) float h1s[16 * HS];
  __shared__ __align__(16) float w2s[256 * 16];
  const int r0 = blockIdx.x * 16, t = threadIdx.x;
  for (int i = t; i < 4096; i += 256) {
    int r = i >> 8, k = i & 255;
    float s = b1[k];
#pragma unroll
    for (int p = 0; p < 16; ++p) s += h1p[(size_t)p * 131072 + (size_t)(r0 + r) * 256 + k];
    h1s[r * HS + k] = s;
    w2s[i] = w2[i];
  }
  __syncthreads();
  const int j = t & 15, r = t >> 4;
  float acc = b2[j];
#pragma unroll 4
  for (int k4 = 0; k4 < 64; ++k4) {
    float4 hv = *(const float4*)&h1s[r * HS + 4 * k4];
    float h0 = fmaxf(hv.x, 0.f), h1v = fmaxf(hv.y, 0.f);
    float h2v = fmaxf(hv.z, 0.f), h3 = fmaxf(hv.w, 0.f);
    acc += h0 * w2s[(4 * k4 + 0) * 16 + j];
    acc += h1v * w2s[(4 * k4 + 1) * 16 + j];
    acc += h2v * w2s[(4 * k4 + 2) * 16 + j];
    acc += h3 * w2s[(4 * k4 + 3) * 16 + j];
  }
  float v = fmaxf(acc, 0.f) * sw[j];
#pragma unroll
  for (int off = 8; off; off >>= 1) v += __shfl_xor(v, off, 16);
  if (j == 0) out[r0 + r] = v + sb[0];
}

// =================== launcher ===================
extern "C" void kernel_launch(void* const* d_in, const int* in_sizes, int n_in,
                              void* d_out, int out_size, void* d_ws, size_t ws_size,
                              hipStream_t stream) {
  const float* x_q = (const float*)d_in[0];
  const float* x_c = (const float*)d_in[1];
  const int* edge_q = (const int*)d_in[2];
  const int* edge_c = (const int*)d_in[3];
  const float* gw1 = (const float*)d_in[4];
  const float* gb1 = (const float*)d_in[5];
  const float* gw2 = (const float*)d_in[6];
  const float* gb2 = (const float*)d_in[7];
  const float* gw3 = (const float*)d_in[8];
  const float* gb3 = (const float*)d_in[9];
  const float* cw1 = (const float*)d_in[10];
  const float* cb1 = (const float*)d_in[11];
  const float* cw2 = (const float*)d_in[12];
  const float* cb2 = (const float*)d_in[13];
  const float* cw3 = (const float*)d_in[14];
  const float* cb3 = (const float*)d_in[15];
  const float* lw1 = (const float*)d_in[16];
  const float* lb1 = (const float*)d_in[17];
  const float* lw2 = (const float*)d_in[18];
  const float* lb2 = (const float*)d_in[19];
  const float* swt = (const float*)d_in[20];
  const float* sbs = (const float*)d_in[21];
  float* ws = (float*)d_ws;

  const size_t o_f1q = 65536;
  const size_t o_f2q = o_f1q + 2097152;
  const size_t o_f3q = o_f2q + 1048576;
  const size_t o_f1c = o_f3q + 524288;
  const size_t o_f2c = o_f1c + 2097152;
  const size_t o_f3c = o_f2c + 1048576;
  const size_t o_sims = o_f3c + 524288;
  const size_t o_pm1 = o_sims + 6291456;
  const size_t o_pm2 = o_pm1 + 6291456;
  const size_t o_wT = o_pm2 + 3145728;
  const size_t o_w2p = o_wT + 786432;
  const size_t o_w3p = o_w2p + 8192;
  const size_t o_feat = o_sims;
  const size_t o_h1p = o_f1q;

  u16* f1q = (u16*)(ws + o_f1q); u16* f2q = (u16*)(ws + o_f2q); u16* f3q = (u16*)(ws + o_f3q);
  u16* f1c = (u16*)(ws + o_f1c); u16* f2c = (u16*)(ws + o_f2c); u16* f3c = (u16*)(ws + o_f3c);
  u16* pm1 = (u16*)(ws + o_pm1);
  u16* wT = (u16*)(ws + o_wT);
  u16* w2p = (u16*)(ws + o_w2p);
  u16* w3p = (u16*)(ws + o_w3p);
  u16* feat = (u16*)(ws + o_feat);
  float* h1p = ws + o_h1p;

  prep_kernel<<<580, 256, 0, stream>>>(lw1, cw2, cw3, wT, w2p, w3p);

  gcn_fused<<<dim3(B, 2), 256, 0, stream>>>(x_q, x_c, gw1, gb1, gw2, gb2, gw3, gb3,
                                            edge_q, edge_c, f1q, f1c, f2q, f2c, f3q, f3c);

  simconv1<<<dim3(B, 3), 256, 0, stream>>>(f1q, f1c, f2q, f2c, f3q, f3c, cw1, cb1, pm1);

  conv23_mfma<<<dim3(B, 3), 256, 0, stream>>>(pm1, w2p, cb2, w3p, cb3, feat);

  lin1_mfma<<<dim3(8, 4, 16), 256, 0, stream>>>(feat, wT, h1p);
  head_kernel<<<32, 256, 0, stream>>>(h1p, lb1, lw2, lb2, swt, sbs, (float*)d_out);
}